// Round 9
// baseline (504.991 us; speedup 1.0000x reference)
//
#include <hip/hip_runtime.h>
#include <hip/hip_bf16.h>

#define N_NODES 50000
#define N_EDGES 600000
#define F 128
#define R 2
#define NLAYER 4
#define NSEG (N_NODES * R)  /* 100000 */
#define NSCB 98             /* scan blocks: ceil(100000/1024) */
#define KTOT 384            /* gemm2 K: 128 mm0 + 128 mm1 + 128 hbn */
#define BN_EPS 1e-5f
#define BETA 1e-4f

typedef __hip_bfloat16 bf16;
typedef __attribute__((ext_vector_type(8))) short short8;  // 8 bf16 (4 VGPRs)
typedef __attribute__((ext_vector_type(4))) float floatx4; // 4 fp32 acc

// ---------------- weight pack: Bt2[l][j][k], j=out col, k in [0,384) ----------------
// k<128: W_rel[0][k][j]; k in [128,256): W_rel[1][k-128][j]; k>=256: W_root[k-256][j]
__global__ void k_wt(const float* __restrict__ W0_rel, const float* __restrict__ W0_root,
                     const float* __restrict__ Ws_rel, const float* __restrict__ Ws_root,
                     bf16* __restrict__ Bt2) {
    int idx = blockIdx.x * 256 + threadIdx.x;
    if (idx >= NLAYER * F * KTOT) return;
    int l = idx / (F * KTOT);
    int rem = idx % (F * KTOT);
    int j = rem / KTOT, k = rem % KTOT;
    float v;
    if (k < 256) {
        int r = k >> 7, d = k & 127;
        v = (l == 0) ? W0_rel[((size_t)r * F + d) * F + j]
                     : Ws_rel[((size_t)((l - 1) * R + r) * F + d) * F + j];
    } else {
        int d = k - 256;
        v = (l == 0) ? W0_root[(size_t)d * F + j]
                     : Ws_root[((size_t)(l - 1) * F + d) * F + j];
    }
    Bt2[idx] = __float2bfloat16(v);
}

// ---------------- segment counts ----------------
__global__ void k_count(const int* __restrict__ dst, const int* __restrict__ et,
                        int* __restrict__ cnt) {
    int e = blockIdx.x * 256 + threadIdx.x;
    if (e < N_EDGES) atomicAdd(&cnt[dst[e] * R + et[e]], 1);
}

// ---------------- multi-block exclusive scan of cnt ----------------
__global__ void k_scan1(const int* __restrict__ cnt, int* __restrict__ off,
                        int* __restrict__ bsum) {
    int t = threadIdx.x;
    int g = blockIdx.x * 1024 + t;
    int v = (g < NSEG) ? cnt[g] : 0;
    int lane = t & 63;
    int wv = t >> 6;
    int x = v;
    for (int d = 1; d < 64; d <<= 1) {
        int y = __shfl_up(x, d, 64);
        if (lane >= d) x += y;
    }
    __shared__ int wtot[16];
    if (lane == 63) wtot[wv] = x;
    __syncthreads();
    if (t < 16) {
        int s = wtot[t];
        for (int d = 1; d < 16; d <<= 1) {
            int y = __shfl_up(s, d, 64);
            if (t >= d) s += y;
        }
        wtot[t] = s;
    }
    __syncthreads();
    int wpre = (wv == 0) ? 0 : wtot[wv - 1];
    int incl = x + wpre;
    if (g < NSEG) off[g] = incl - v;  // exclusive within block
    if (t == 1023) bsum[blockIdx.x] = incl;
}

__global__ void k_scan2(int* __restrict__ bsum) {
    __shared__ int s[128];
    int t = threadIdx.x;
    int v = (t < NSCB) ? bsum[t] : 0;
    s[t] = v;
    __syncthreads();
    for (int d = 1; d < 128; d <<= 1) {
        int y = (t >= d) ? s[t - d] : 0;
        __syncthreads();
        s[t] += y;
        __syncthreads();
    }
    if (t < NSCB) bsum[t] = s[t] - v;  // exclusive
}

__global__ void k_scan3(int* __restrict__ off, const int* __restrict__ bsum) {
    int g = blockIdx.x * 1024 + threadIdx.x;
    if (g < NSEG) off[g] += bsum[blockIdx.x];
}

// ---------------- fill segment-sorted src list ----------------
__global__ void k_fill(const int* __restrict__ src, const int* __restrict__ dst,
                       const int* __restrict__ et, const int* __restrict__ off,
                       int* __restrict__ fill, int* __restrict__ esrc) {
    int e = blockIdx.x * 256 + threadIdx.x;
    if (e >= N_EDGES) return;
    int seg = dst[e] * R + et[e];
    int idx = off[seg] + atomicAdd(&fill[seg], 1);
    esrc[idx] = src[e];
}

// ---------------- BN column stats: gs[0..127]=sum, gs[128..255]=sumsq ----------------
__global__ void k_bnstats(const float* __restrict__ h, float* __restrict__ gs) {
    int c = threadIdx.x & 127;
    int rl = threadIdx.x >> 7;
    float s = 0.f, q = 0.f;
    for (int r = blockIdx.x * 2 + rl; r < N_NODES; r += gridDim.x * 2) {
        float v = h[(size_t)r * F + c];
        s += v; q += v * v;
    }
    __shared__ float ls[256], lq[256];
    ls[threadIdx.x] = s; lq[threadIdx.x] = q;
    __syncthreads();
    if (rl == 0) {
        atomicAdd(&gs[c], ls[c] + ls[c + 128]);
        atomicAdd(&gs[128 + c], lq[c] + lq[c + 128]);
    }
}

// ---------------- BN apply: hbn = bf16(bn(hin)) ----------------
__global__ void k_bn(const float* __restrict__ hin, const float* __restrict__ gs,
                     bf16* __restrict__ hbn) {
    int idx = blockIdx.x * 256 + threadIdx.x;       // quad index
    if (idx >= N_NODES * F / 4) return;
    int c4 = (idx * 4) & 127;
    float4 v = *(const float4*)(hin + (size_t)idx * 4);
    bf16 o[4];
    float vv[4] = {v.x, v.y, v.z, v.w};
    #pragma unroll
    for (int c = 0; c < 4; c++) {
        float mm = gs[c4 + c] * (1.0f / N_NODES);
        float qq = gs[128 + c4 + c] * (1.0f / N_NODES);
        float rs = rsqrtf(qq - mm * mm + BN_EPS);
        o[c] = __float2bfloat16((vv[c] - mm) * rs + BETA);
    }
    *(double*)(hbn + (size_t)idx * 4) = *(const double*)o;
}

// ---------------- per-(node,rel) mean of hbn[src] rows -> mm ----------------
__device__ __forceinline__ void seg_sum(const bf16* __restrict__ hb,
                                        const int* __restrict__ esrc,
                                        int o, int c, float& rx, float& ry) {
    float a0 = 0.f, a1 = 0.f, b0 = 0.f, b1 = 0.f;
    float e0 = 0.f, e1 = 0.f, d0 = 0.f, d1 = 0.f;
    int i = 0;
    for (; i + 4 <= c; i += 4) {
        int s0 = esrc[o + i], s1 = esrc[o + i + 1];
        int s2 = esrc[o + i + 2], s3 = esrc[o + i + 3];
        __hip_bfloat162 p0 = *(const __hip_bfloat162*)(hb + (size_t)s0 * F);
        __hip_bfloat162 p1 = *(const __hip_bfloat162*)(hb + (size_t)s1 * F);
        __hip_bfloat162 p2 = *(const __hip_bfloat162*)(hb + (size_t)s2 * F);
        __hip_bfloat162 p3 = *(const __hip_bfloat162*)(hb + (size_t)s3 * F);
        a0 += __bfloat162float(p0.x); a1 += __bfloat162float(p0.y);
        b0 += __bfloat162float(p1.x); b1 += __bfloat162float(p1.y);
        e0 += __bfloat162float(p2.x); e1 += __bfloat162float(p2.y);
        d0 += __bfloat162float(p3.x); d1 += __bfloat162float(p3.y);
    }
    for (; i < c; i++) {
        int sn = esrc[o + i];
        __hip_bfloat162 p = *(const __hip_bfloat162*)(hb + (size_t)sn * F);
        a0 += __bfloat162float(p.x); a1 += __bfloat162float(p.y);
    }
    rx = (a0 + b0) + (e0 + d0);
    ry = (a1 + b1) + (e1 + d1);
}

__global__ void k_agg(const bf16* __restrict__ hbn,
                      const int* __restrict__ cnt, const int* __restrict__ off,
                      const int* __restrict__ esrc, bf16* __restrict__ mm) {
    int wid = (blockIdx.x * 256 + threadIdx.x) >> 6;
    int lane = threadIdx.x & 63;
    if (wid >= N_NODES) return;
    int n = wid;
    int f = lane * 2;
    int2 cc = *(const int2*)(cnt + n * R);
    int c0 = cc.x, c1 = cc.y;
    int o0 = off[n * R];
    float inv0 = (c0 > 0) ? 1.0f / (float)c0 : 0.f;
    float inv1 = (c1 > 0) ? 1.0f / (float)c1 : 0.f;
    const bf16* hb = hbn + f;
    float s0x, s0y, s1x, s1y;
    seg_sum(hb, esrc, o0, c0, s0x, s0y);
    seg_sum(hb, esrc, o0 + c0, c1, s1x, s1y);
    __hip_bfloat162 w0, w1;
    w0.x = __float2bfloat16(s0x * inv0);
    w0.y = __float2bfloat16(s0y * inv0);
    w1.x = __float2bfloat16(s1x * inv1);
    w1.y = __float2bfloat16(s1y * inv1);
    *(__hip_bfloat162*)(mm + (size_t)n * 256 + f) = w0;
    *(__hip_bfloat162*)(mm + (size_t)n * 256 + 128 + f) = w1;
}

// ---------------- K=384 GEMM: out = [mm|hbn] @ Bt2 + b, relu+residual fused ----------------
// Block = 64 rows x 128 cols, 512 threads, 3 K-chunks of 128. Swapped-operand
// MFMA (D^T): lane holds out[m][n0..n0+3] -> float4 stores of h (and d_out).
__launch_bounds__(512)
__global__ void k_gemm2(const bf16* __restrict__ mm, const bf16* __restrict__ hbn,
                        const bf16* __restrict__ Bt2, const float* __restrict__ bias,
                        float* __restrict__ h, float* __restrict__ outp, int layer) {
    __shared__ bf16 As[64 * 136];    // 17.4 KB
    __shared__ bf16 Bs[128 * 136];   // 34.8 KB
    int t = threadIdx.x;
    int m0 = blockIdx.x * 64;
    int w = t >> 6;
    int lane = t & 63;
    int msub = w & 3;   // m-subtile 0..3
    int nh = w >> 2;    // n-half 0..1
    int lm = lane & 15;
    int lq = lane >> 4;
    int m = m0 + msub * 16 + lm;
    floatx4 acc[4];
    #pragma unroll
    for (int j = 0; j < 4; j++) acc[j] = (floatx4){0.f, 0.f, 0.f, 0.f};
    for (int ci = 0; ci < 3; ci++) {
        __syncthreads();  // previous chunk's readers done
        // stage As chunk: rows m0..m0+63, K cols [ci*128, ci*128+128)
        {
            for (int rr = 0; rr < 2; rr++) {
                int idx = rr * 512 + t;   // 0..1023
                int row = idx >> 4;       // 0..63
                int kc = idx & 15;        // 16B chunk
                const bf16* srcp = (ci < 2)
                    ? (mm + (size_t)(m0 + row) * 256 + ci * 128 + kc * 8)
                    : (hbn + (size_t)(m0 + row) * F + kc * 8);
                *(short8*)(As + row * 136 + kc * 8) = *(const short8*)srcp;
            }
        }
        // stage Bs chunk: j rows 0..127, K cols [ci*128, ci*128+128)
        {
            for (int rr = 0; rr < 4; rr++) {
                int idx = rr * 512 + t;   // 0..2047
                int row = idx >> 4;       // 0..127
                int kc = idx & 15;
                short8 v = *(const short8*)(Bt2 + (size_t)row * KTOT + ci * 128 + kc * 8);
                *(short8*)(Bs + row * 136 + kc * 8) = v;
            }
        }
        __syncthreads();
        short8 a[4];
        #pragma unroll
        for (int ki = 0; ki < 4; ki++)
            a[ki] = *(const short8*)(As + (msub * 16 + lm) * 136 + ki * 32 + lq * 8);
        for (int tt = 0; tt < 4; tt++) {
            int nt = nh * 4 + tt;   // n-tile 0..7
            short8 b[4];
            #pragma unroll
            for (int ki = 0; ki < 4; ki++)
                b[ki] = *(const short8*)(Bs + (nt * 16 + lm) * 136 + ki * 32 + lq * 8);
            #pragma unroll
            for (int ki = 0; ki < 4; ki++)
                acc[tt] = __builtin_amdgcn_mfma_f32_16x16x32_bf16(b[ki], a[ki], acc[tt], 0, 0, 0);
        }
    }
    // epilogue: bias + relu + residual, float4 stores
    if (m < N_NODES) {
        #pragma unroll
        for (int tt = 0; tt < 4; tt++) {
            int nt = nh * 4 + tt;
            int n0 = nt * 16 + lq * 4;
            float4 bv = *(const float4*)(bias + n0);
            float4 hv = {0.f, 0.f, 0.f, 0.f};
            if (layer > 0) hv = *(const float4*)(h + (size_t)m * F + n0);
            float4 o4;
            o4.x = fmaxf(acc[tt][0] + bv.x, 0.f) + hv.x;
            o4.y = fmaxf(acc[tt][1] + bv.y, 0.f) + hv.y;
            o4.z = fmaxf(acc[tt][2] + bv.z, 0.f) + hv.z;
            o4.w = fmaxf(acc[tt][3] + bv.w, 0.f) + hv.w;
            *(float4*)(h + (size_t)m * F + n0) = o4;
            if (outp) *(float4*)(outp + (size_t)m * F + n0) = o4;
        }
    }
}

extern "C" void kernel_launch(void* const* d_in, const int* in_sizes, int n_in,
                              void* d_out, int out_size, void* d_ws, size_t ws_size,
                              hipStream_t stream) {
    const float* x       = (const float*)d_in[0];
    const int*   eidx    = (const int*)d_in[1];
    const int*   etype   = (const int*)d_in[2];
    const float* W0_rel  = (const float*)d_in[3];
    const float* W0_root = (const float*)d_in[4];
    const float* b0      = (const float*)d_in[5];
    const float* Ws_rel  = (const float*)d_in[6];
    const float* Ws_root = (const float*)d_in[7];
    const float* bs      = (const float*)d_in[8];
    const int* src = eidx;
    const int* dst = eidx + N_EDGES;

    char* w = (char*)d_ws;
    float* h   = (float*)w; w += (size_t)N_NODES * F * 4;      // 25.6 MB
    bf16*  hbn = (bf16*)w;  w += (size_t)N_NODES * F * 2;      // 12.8 MB
    bf16*  mm  = (bf16*)w;  w += (size_t)N_NODES * 256 * 2;    // 25.6 MB
    bf16*  Bt2 = (bf16*)w;  w += (size_t)NLAYER * F * KTOT * 2; // 384 KB
    int* cnt   = (int*)w;   w += (size_t)NSEG * 4;             // contiguous zero region:
    int* fill  = (int*)w;   w += (size_t)NSEG * 4;             //   cnt | fill | stats
    float* stats = (float*)w; w += (size_t)NLAYER * 256 * 4;
    int* off   = (int*)w;   w += (size_t)NSEG * 4;
    int* esrc  = (int*)w;   w += (size_t)N_EDGES * 4;
    int* bsum  = (int*)w;   w += 128 * 4;                      // total ~67 MB

    hipMemsetAsync(cnt, 0, (size_t)NSEG * 4 * 2 + (size_t)NLAYER * 256 * 4, stream);
    k_wt<<<(NLAYER * F * KTOT + 255) / 256, 256, 0, stream>>>(W0_rel, W0_root, Ws_rel, Ws_root, Bt2);
    k_count<<<(N_EDGES + 255) / 256, 256, 0, stream>>>(dst, etype, cnt);
    k_scan1<<<NSCB, 1024, 0, stream>>>(cnt, off, bsum);
    k_scan2<<<1, 128, 0, stream>>>(bsum);
    k_scan3<<<NSCB, 1024, 0, stream>>>(off, bsum);
    k_fill<<<(N_EDGES + 255) / 256, 256, 0, stream>>>(src, dst, etype, off, fill, esrc);

    for (int l = 0; l < NLAYER; l++) {
        float* gs = stats + l * 256;
        const float* bias = (l == 0) ? b0 : (bs + (size_t)(l - 1) * F);
        const float* hin = (l == 0) ? x : h;
        k_bnstats<<<512, 256, 0, stream>>>(hin, gs);
        k_bn<<<(N_NODES * F / 4 + 255) / 256, 256, 0, stream>>>(hin, gs, hbn);
        k_agg<<<(N_NODES * 64 + 255) / 256, 256, 0, stream>>>(hbn, cnt, off, esrc, mm);
        k_gemm2<<<(N_NODES + 63) / 64, 512, 0, stream>>>(
            mm, hbn, Bt2 + (size_t)l * F * KTOT, bias, h,
            (l == 3) ? (float*)d_out : nullptr, l);
    }
}